// Round 5
// baseline (211.182 us; speedup 1.0000x reference)
//
#include <hip/hip_runtime.h>

#define S_LEN 4096
#define NROWS 16384   // B*S

typedef __attribute__((ext_vector_type(8))) __bf16 bf16x8;
typedef __attribute__((ext_vector_type(8))) unsigned short ushort8;
typedef __attribute__((ext_vector_type(4))) float floatx4;

__device__ __forceinline__ unsigned short f2bf(float f) {   // RNE
    unsigned int u = __float_as_uint(f);
    unsigned int r = (u + 0x7fffu + ((u >> 16) & 1u)) >> 16;
    return (unsigned short)r;
}

__device__ __forceinline__ float fexp2(float x) {
#if __has_builtin(__builtin_amdgcn_exp2f)
    return __builtin_amdgcn_exp2f(x);
#else
    float r; asm("v_exp_f32 %0, %1" : "=v"(r) : "v"(x)); return r;
#endif
}

__device__ __forceinline__ bf16x8 cvt_bf16x8(float4 a, float4 b) {
    union { ushort8 u; bf16x8 v; } r;
    r.u[0] = f2bf(a.x); r.u[1] = f2bf(a.y); r.u[2] = f2bf(a.z); r.u[3] = f2bf(a.w);
    r.u[4] = f2bf(b.x); r.u[5] = f2bf(b.y); r.u[6] = f2bf(b.z); r.u[7] = f2bf(b.w);
    return r.v;
}

// ---------------- K0: weights fp32 -> bf16 transposed (unchanged, proven)
__global__ __launch_bounds__(256) void convw_kernel(
    const float* __restrict__ Wq, const float* __restrict__ Wk,
    const float* __restrict__ Wv, const float* __restrict__ Wo,
    unsigned short* __restrict__ WqT, unsigned short* __restrict__ WkT,
    unsigned short* __restrict__ WvT, unsigned short* __restrict__ WoT)
{
    int tid = blockIdx.x * 256 + threadIdx.x;   // 0..32767
    int n = tid >> 9, k = tid & 511;            // (n<64, k<512)
    WqT[tid] = f2bf(Wq[k * 64 + n]);
    WkT[tid] = f2bf(Wk[k * 64 + n]);
    WvT[tid] = f2bf(Wv[k * 64 + n]);
    int n2 = tid >> 6, k2 = tid & 63;           // (n2<512, k2<64)
    WoT[tid] = f2bf(Wo[k2 * 512 + n2]);
}

// ---------------- K1: QKV projection, FUSED: one block computes Q,K,V for
// its 16-row tile (wave w -> matrix w), so x is fetched from HBM once
// instead of 3x (96 MB -> 32 MB); waves share x via per-CU L1/L2.
// Q pre-scaled by log2(e)/sqrt(4096) (proven).
__global__ __launch_bounds__(192) void qkv_kernel(
    const float* __restrict__ x,
    const unsigned short* __restrict__ WqT, const unsigned short* __restrict__ WkT,
    const unsigned short* __restrict__ WvT,
    const float* __restrict__ bq, const float* __restrict__ bk, const float* __restrict__ bv,
    unsigned short* __restrict__ Qb, unsigned short* __restrict__ Kb,
    unsigned short* __restrict__ Vt)
{
    const int row0 = blockIdx.x * 16;
    const int tid = threadIdx.x;
    const int m = tid >> 6;              // wave id: 0=Q, 1=K, 2=V
    const int lane = tid & 63, cl = lane & 15, quad = lane >> 4;
    const unsigned short* WT = (m == 0) ? WqT : (m == 1) ? WkT : WvT;
    const float* bias = (m == 0) ? bq : (m == 1) ? bk : bv;

    floatx4 acc[4];
    #pragma unroll
    for (int t = 0; t < 4; t++) acc[t] = (floatx4){0.f, 0.f, 0.f, 0.f};
    const float* xrow = x + (size_t)(row0 + cl) * 512;
    #pragma unroll 2
    for (int kc = 0; kc < 16; kc++) {
        const int k0 = kc * 32 + quad * 8;
        float4 xa = *(const float4*)(xrow + k0);
        float4 xb = *(const float4*)(xrow + k0 + 4);
        bf16x8 af = cvt_bf16x8(xa, xb);
        #pragma unroll
        for (int t = 0; t < 4; t++) {
            bf16x8 bf = *(const bf16x8*)(const void*)(WT + (t * 16 + cl) * 512 + k0);
            acc[t] = __builtin_amdgcn_mfma_f32_16x16x32_bf16(af, bf, acc[t], 0, 0, 0);
        }
    }
    if (m < 2) {
        const float scl = (m == 0) ? 0.022542110013890054f : 1.0f;  // log2(e)/64 on Q only
        unsigned short* outp = (m == 0) ? Qb : Kb;
        #pragma unroll
        for (int t = 0; t < 4; t++) {
            const int d = t * 16 + cl;
            const float bd = bias[d];
            #pragma unroll
            for (int r = 0; r < 4; r++)
                outp[(size_t)(row0 + quad * 4 + r) * 64 + d] = f2bf((acc[t][r] + bd) * scl);
        }
    } else {
        const int b = row0 >> 12, s_base = row0 & 4095;
        #pragma unroll
        for (int t = 0; t < 4; t++) {
            const int d = t * 16 + cl;
            const float bd = bias[d];
            #pragma unroll
            for (int r = 0; r < 4; r++)
                Vt[((size_t)b * 64 + d) * S_LEN + s_base + quad * 4 + r] = f2bf(acc[t][r] + bd);
        }
    }
}

// ---------------- K2: causal flash attention, max-free softmax, SPLIT-K x4.
// Changes this round:
//  * REMOVED the per-strip `asm volatile(s_waitcnt lgkmcnt(0) ::: memory)`
//    fences. The "memory" clobber was a full scheduling fence present in
//    every prior variant -- it blocked hoisting the next strip's global
//    loads and serialized each 128-key strip on its full load+LDS latency.
//    The compiler inserts the precise lgkmcnt for the Pw RAW on its own.
//  * SPLIT-K x4: each (b,qt) -> 4 blocks over tile ranges [h*nkt/4,(h+1)*nkt/4).
//    Grid 4096 (16 blocks/CU of inventory vs 4). Max-free math makes the
//    merge a PLAIN SUM of unnormalized partials -- no m bookkeeping.
//    Po partials are staged in d_out (16.8 MB < 32 MB; oproj overwrites later).
#define PSTR 152   // P-strip row stride (ushorts): 76 dwords -> 2-way bank aliasing (free)
__global__ __launch_bounds__(256, 2) void attn_kernel(
    const unsigned short* __restrict__ Qb, const unsigned short* __restrict__ Kb,
    const unsigned short* __restrict__ Vt,
    float* __restrict__ Po, float* __restrict__ Pl)
{
    // per-wave region: ps (16*PSTR u16 = 4864 B) unioned with op (16*66 f32 = 4224 B)
    __shared__ float4 shraw[4][304];     // 4864 B per wave, 16B aligned
    __shared__ float Ml[4][16];          // per-row l partial
    const int bid = blockIdx.x;              // 0..4095
    const int pair = bid >> 2, h = bid & 3;
    const int qt = 255 - (pair >> 2);        // longest-first (LPT)
    const int b = pair & 3;
    const int q0 = qt * 16;
    const int nkt = (qt >> 2) + 1;           // 64-key tiles in causal range
    const int kt0 = (h * nkt) >> 2;          // this block's tile range [kt0,kt1)
    const int kt1 = ((h + 1) * nkt) >> 2;
    const int tid = threadIdx.x;
    const int w = tid >> 6, lane = tid & 63, cl = lane & 15, quad = lane >> 4;

    const size_t qrow = (size_t)b * S_LEN + q0 + cl;
    const bf16x8 aq0 = *(const bf16x8*)(const void*)(Qb + qrow * 64 + quad * 8);
    const bf16x8 aq1 = *(const bf16x8*)(const void*)(Qb + qrow * 64 + 32 + quad * 8);
    const unsigned short* kbb = Kb + (size_t)b * S_LEN * 64;
    const unsigned short* vbb = Vt + (size_t)b * 64 * S_LEN;

    float lrow[4];
    floatx4 Oacc[4];
    #pragma unroll
    for (int r = 0; r < 4; r++) lrow[r] = 0.f;
    #pragma unroll
    for (int u = 0; u < 4; u++) Oacc[u] = (floatx4){0.f, 0.f, 0.f, 0.f};

    unsigned short* Pw = (unsigned short*)&shraw[w][0];

    int jt = kt0 + w;
    // -------- paired 128-key strips: tiles (jt, jt+4) within [kt0,kt1) ----
    for (; jt + 4 < kt1; jt += 8) {
        const int j0a = jt * 64, j0b = (jt + 4) * 64;
        float z[8][4];
        bf16x8 vf[8][2];
        // tile A: K frags + QK
        {
            bf16x8 kf[4][2];
            #pragma unroll
            for (int t = 0; t < 4; t++) {
                const unsigned short* kp = kbb + (size_t)(j0a + t * 16 + cl) * 64 + quad * 8;
                kf[t][0] = *(const bf16x8*)(const void*)kp;
                kf[t][1] = *(const bf16x8*)(const void*)(kp + 32);
            }
            #pragma unroll
            for (int t = 0; t < 4; t++) {
                floatx4 acc = (floatx4){0.f, 0.f, 0.f, 0.f};
                acc = __builtin_amdgcn_mfma_f32_16x16x32_bf16(aq0, kf[t][0], acc, 0, 0, 0);
                acc = __builtin_amdgcn_mfma_f32_16x16x32_bf16(aq1, kf[t][1], acc, 0, 0, 0);
                #pragma unroll
                for (int r = 0; r < 4; r++) z[t][r] = acc[r];
            }
        }
        #pragma unroll
        for (int u = 0; u < 4; u++) {
            const unsigned short* vp = vbb + (size_t)(u * 16 + cl) * S_LEN + j0a + quad * 8;
            vf[u][0] = *(const bf16x8*)(const void*)vp;
            vf[u][1] = *(const bf16x8*)(const void*)(vp + 32);
        }
        // tile B: K frags + QK
        {
            bf16x8 kf[4][2];
            #pragma unroll
            for (int t = 0; t < 4; t++) {
                const unsigned short* kp = kbb + (size_t)(j0b + t * 16 + cl) * 64 + quad * 8;
                kf[t][0] = *(const bf16x8*)(const void*)kp;
                kf[t][1] = *(const bf16x8*)(const void*)(kp + 32);
            }
            #pragma unroll
            for (int t = 0; t < 4; t++) {
                floatx4 acc = (floatx4){0.f, 0.f, 0.f, 0.f};
                acc = __builtin_amdgcn_mfma_f32_16x16x32_bf16(aq0, kf[t][0], acc, 0, 0, 0);
                acc = __builtin_amdgcn_mfma_f32_16x16x32_bf16(aq1, kf[t][1], acc, 0, 0, 0);
                #pragma unroll
                for (int r = 0; r < 4; r++) z[4 + t][r] = acc[r];
            }
        }
        #pragma unroll
        for (int u = 0; u < 4; u++) {
            const unsigned short* vp = vbb + (size_t)(u * 16 + cl) * S_LEN + j0b + quad * 8;
            vf[4 + u][0] = *(const bf16x8*)(const void*)vp;
            vf[4 + u][1] = *(const bf16x8*)(const void*)(vp + 32);
        }
        // mask: only the globally-last tile can need it
        if (jt + 4 == nkt - 1) {
            #pragma unroll
            for (int t = 0; t < 4; t++)
                #pragma unroll
                for (int r = 0; r < 4; r++)
                    if (j0b + t * 16 + cl > q0 + quad * 4 + r) z[4 + t][r] = -1e30f;
        }
        // direct softmax numerator: p = exp2(z) (no max shift needed)
        #pragma unroll
        for (int t = 0; t < 8; t++)
            #pragma unroll
            for (int r = 0; r < 4; r++) z[t][r] = fexp2(z[t][r]);
        #pragma unroll
        for (int r = 0; r < 4; r++)
            lrow[r] += ((z[0][r] + z[1][r]) + (z[2][r] + z[3][r]))
                     + ((z[4][r] + z[5][r]) + (z[6][r] + z[7][r]));
        // P strip 16x128 -> A-layout via wave-local LDS (compiler inserts waits)
        #pragma unroll
        for (int t = 0; t < 8; t++)
            #pragma unroll
            for (int r = 0; r < 4; r++)
                Pw[(quad * 4 + r) * PSTR + t * 16 + cl] = f2bf(z[t][r]);
        bf16x8 ap0 = *(const bf16x8*)(const void*)(Pw + cl * PSTR + quad * 8);
        bf16x8 ap1 = *(const bf16x8*)(const void*)(Pw + cl * PSTR + 32 + quad * 8);
        bf16x8 ap2 = *(const bf16x8*)(const void*)(Pw + cl * PSTR + 64 + quad * 8);
        bf16x8 ap3 = *(const bf16x8*)(const void*)(Pw + cl * PSTR + 96 + quad * 8);
        #pragma unroll
        for (int u = 0; u < 4; u++) {
            Oacc[u] = __builtin_amdgcn_mfma_f32_16x16x32_bf16(ap0, vf[u][0], Oacc[u], 0, 0, 0);
            Oacc[u] = __builtin_amdgcn_mfma_f32_16x16x32_bf16(ap1, vf[u][1], Oacc[u], 0, 0, 0);
            Oacc[u] = __builtin_amdgcn_mfma_f32_16x16x32_bf16(ap2, vf[4 + u][0], Oacc[u], 0, 0, 0);
            Oacc[u] = __builtin_amdgcn_mfma_f32_16x16x32_bf16(ap3, vf[4 + u][1], Oacc[u], 0, 0, 0);
        }
    }
    // -------- leftover single tile --------
    if (jt < kt1) {
        const int j0 = jt * 64;
        bf16x8 kf[4][2], vf[4][2];
        #pragma unroll
        for (int t = 0; t < 4; t++) {
            const unsigned short* kp = kbb + (size_t)(j0 + t * 16 + cl) * 64 + quad * 8;
            kf[t][0] = *(const bf16x8*)(const void*)kp;
            kf[t][1] = *(const bf16x8*)(const void*)(kp + 32);
        }
        #pragma unroll
        for (int u = 0; u < 4; u++) {
            const unsigned short* vp = vbb + (size_t)(u * 16 + cl) * S_LEN + j0 + quad * 8;
            vf[u][0] = *(const bf16x8*)(const void*)vp;
            vf[u][1] = *(const bf16x8*)(const void*)(vp + 32);
        }
        float z[4][4];
        #pragma unroll
        for (int t = 0; t < 4; t++) {
            floatx4 acc = (floatx4){0.f, 0.f, 0.f, 0.f};
            acc = __builtin_amdgcn_mfma_f32_16x16x32_bf16(aq0, kf[t][0], acc, 0, 0, 0);
            acc = __builtin_amdgcn_mfma_f32_16x16x32_bf16(aq1, kf[t][1], acc, 0, 0, 0);
            #pragma unroll
            for (int r = 0; r < 4; r++) z[t][r] = acc[r];
        }
        if (jt == nkt - 1) {
            #pragma unroll
            for (int t = 0; t < 4; t++)
                #pragma unroll
                for (int r = 0; r < 4; r++)
                    if (j0 + t * 16 + cl > q0 + quad * 4 + r) z[t][r] = -1e30f;
        }
        #pragma unroll
        for (int t = 0; t < 4; t++)
            #pragma unroll
            for (int r = 0; r < 4; r++) z[t][r] = fexp2(z[t][r]);
        #pragma unroll
        for (int r = 0; r < 4; r++)
            lrow[r] += ((z[0][r] + z[1][r]) + (z[2][r] + z[3][r]));
        #pragma unroll
        for (int t = 0; t < 4; t++)
            #pragma unroll
            for (int r = 0; r < 4; r++)
                Pw[(quad * 4 + r) * PSTR + t * 16 + cl] = f2bf(z[t][r]);
        bf16x8 ap0 = *(const bf16x8*)(const void*)(Pw + cl * PSTR + quad * 8);
        bf16x8 ap1 = *(const bf16x8*)(const void*)(Pw + cl * PSTR + 32 + quad * 8);
        #pragma unroll
        for (int u = 0; u < 4; u++) {
            Oacc[u] = __builtin_amdgcn_mfma_f32_16x16x32_bf16(ap0, vf[u][0], Oacc[u], 0, 0, 0);
            Oacc[u] = __builtin_amdgcn_mfma_f32_16x16x32_bf16(ap1, vf[u][1], Oacc[u], 0, 0, 0);
        }
    }
    // one cross-lane l reduce (sum over the 16 col-classes)
    #pragma unroll
    for (int r = 0; r < 4; r++) {
        float s = lrow[r];
        s += __shfl_xor(s, 1, 64);
        s += __shfl_xor(s, 2, 64);
        s += __shfl_xor(s, 4, 64);
        s += __shfl_xor(s, 8, 64);
        lrow[r] = s;
    }
    // publish partials (op region overlays ps region; same wave, ps reads done)
    {
        float* Opw = (float*)&shraw[w][0];   // [16][66]
        #pragma unroll
        for (int u = 0; u < 4; u++)
            #pragma unroll
            for (int r = 0; r < 4; r++)
                Opw[(quad * 4 + r) * 66 + u * 16 + cl] = Oacc[u][r];
        if (cl == 0) {
            #pragma unroll
            for (int r = 0; r < 4; r++) Ml[w][quad * 4 + r] = lrow[r];
        }
    }
    __syncthreads();
    {
        const int row = tid >> 4, d0 = (tid & 15) * 4;
        const float L = Ml[0][row] + Ml[1][row] + Ml[2][row] + Ml[3][row];
        const float* o0 = (const float*)&shraw[0][0];
        const float* o1 = (const float*)&shraw[1][0];
        const float* o2 = (const float*)&shraw[2][0];
        const float* o3 = (const float*)&shraw[3][0];
        float4 o;
        o.x = o0[row * 66 + d0 + 0] + o1[row * 66 + d0 + 0]
            + o2[row * 66 + d0 + 0] + o3[row * 66 + d0 + 0];
        o.y = o0[row * 66 + d0 + 1] + o1[row * 66 + d0 + 1]
            + o2[row * 66 + d0 + 1] + o3[row * 66 + d0 + 1];
        o.z = o0[row * 66 + d0 + 2] + o1[row * 66 + d0 + 2]
            + o2[row * 66 + d0 + 2] + o3[row * 66 + d0 + 2];
        o.w = o0[row * 66 + d0 + 3] + o1[row * 66 + d0 + 3]
            + o2[row * 66 + d0 + 3] + o3[row * 66 + d0 + 3];
        *(float4*)(Po + ((size_t)bid * 16 + row) * 64 + d0) = o;  // unnormalized
        if (d0 == 0) Pl[(size_t)bid * 16 + row] = L;
    }
}

// ---------------- K2b: sum the 4 split-K partials -> normalized bf16 Ob
__global__ __launch_bounds__(256) void amerge_kernel(
    const float* __restrict__ Po, const float* __restrict__ Pl,
    unsigned short* __restrict__ Ob)
{
    const int pair = blockIdx.x;             // 0..1023
    const int qt = 255 - (pair >> 2), b = pair & 3;
    const int row = threadIdx.x >> 4, d0 = (threadIdx.x & 15) * 4;
    const size_t base = (size_t)pair * 4;
    const float L = Pl[(base + 0) * 16 + row] + Pl[(base + 1) * 16 + row]
                  + Pl[(base + 2) * 16 + row] + Pl[(base + 3) * 16 + row];
    const float invL = 1.0f / L;
    const float4 a0 = *(const float4*)(Po + ((base + 0) * 16 + row) * 64 + d0);
    const float4 a1 = *(const float4*)(Po + ((base + 1) * 16 + row) * 64 + d0);
    const float4 a2 = *(const float4*)(Po + ((base + 2) * 16 + row) * 64 + d0);
    const float4 a3 = *(const float4*)(Po + ((base + 3) * 16 + row) * 64 + d0);
    unsigned short ov[4];
    ov[0] = f2bf((a0.x + a1.x + a2.x + a3.x) * invL);
    ov[1] = f2bf((a0.y + a1.y + a2.y + a3.y) * invL);
    ov[2] = f2bf((a0.z + a1.z + a2.z + a3.z) * invL);
    ov[3] = f2bf((a0.w + a1.w + a2.w + a3.w) * invL);
    *(uint2*)(void*)(Ob + ((size_t)b * S_LEN + qt * 16 + row) * 64 + d0) = *(const uint2*)ov;
}

// ---------------- K3: out = O @ Wo + bo via MFMA (unchanged, proven)
__global__ __launch_bounds__(256) void oproj_kernel(
    const unsigned short* __restrict__ Ob, const unsigned short* __restrict__ WoT,
    const float* __restrict__ bo, float* __restrict__ out)
{
    const int row0 = blockIdx.x * 16;
    const int tid = threadIdx.x;
    const int w = tid >> 6, lane = tid & 63, cl = lane & 15, quad = lane >> 4;
    const unsigned short* op = Ob + (size_t)(row0 + cl) * 64 + quad * 8;
    const bf16x8 a0 = *(const bf16x8*)(const void*)op;
    const bf16x8 a1 = *(const bf16x8*)(const void*)(op + 32);
    #pragma unroll 2
    for (int i = 0; i < 8; i++) {
        const int n = w * 128 + i * 16 + cl;
        const unsigned short* wp = WoT + (size_t)n * 64 + quad * 8;
        bf16x8 b0 = *(const bf16x8*)(const void*)wp;
        bf16x8 b1 = *(const bf16x8*)(const void*)(wp + 32);
        floatx4 acc = (floatx4){0.f, 0.f, 0.f, 0.f};
        acc = __builtin_amdgcn_mfma_f32_16x16x32_bf16(a0, b0, acc, 0, 0, 0);
        acc = __builtin_amdgcn_mfma_f32_16x16x32_bf16(a1, b1, acc, 0, 0, 0);
        const float bod = bo[n];
        #pragma unroll
        for (int r = 0; r < 4; r++)
            out[(size_t)(row0 + quad * 4 + r) * 512 + n] = acc[r] + bod;
    }
}

extern "C" void kernel_launch(void* const* d_in, const int* in_sizes, int n_in,
                              void* d_out, int out_size, void* d_ws, size_t ws_size,
                              hipStream_t stream) {
    const float* x  = (const float*)d_in[0];
    const float* Wq = (const float*)d_in[1];
    const float* bq = (const float*)d_in[2];
    const float* Wk = (const float*)d_in[3];
    const float* bk = (const float*)d_in[4];
    const float* Wv = (const float*)d_in[5];
    const float* bv = (const float*)d_in[6];
    const float* Wo = (const float*)d_in[7];
    const float* bo = (const float*)d_in[8];
    float* out = (float*)d_out;

    unsigned short* Qb  = (unsigned short*)d_ws;               // 2 MB
    unsigned short* Kb  = Qb + (size_t)NROWS * 64;             // 2 MB
    unsigned short* Vt  = Kb + (size_t)NROWS * 64;             // 2 MB (transposed [b][64][s])
    unsigned short* Ob  = Vt + (size_t)NROWS * 64;             // 2 MB (bf16 O, row-major)
    unsigned short* WqT = Ob + (size_t)NROWS * 64;             // 64 KB each
    unsigned short* WkT = WqT + 512 * 64;
    unsigned short* WvT = WkT + 512 * 64;
    unsigned short* WoT = WvT + 512 * 64;
    float* Pl = (float*)(WoT + 512 * 64);                      // 4096*16 f32 = 256 KB
    // Po partials live in d_out (16.8 MB < 32 MB); oproj overwrites out after.
    float* Po = out;

    convw_kernel<<<128, 256, 0, stream>>>(Wq, Wk, Wv, Wo, WqT, WkT, WvT, WoT);
    qkv_kernel<<<1024, 192, 0, stream>>>(x, WqT, WkT, WvT, bq, bk, bv, Qb, Kb, Vt);
    attn_kernel<<<4096, 256, 0, stream>>>(Qb, Kb, Vt, Po, Pl);
    amerge_kernel<<<1024, 256, 0, stream>>>(Po, Pl, Ob);
    oproj_kernel<<<NROWS / 16, 256, 0, stream>>>(Ob, WoT, bo, out);
}

// Round 6
// 172.348 us; speedup vs baseline: 1.2253x; 1.2253x over previous
//
#include <hip/hip_runtime.h>

#define S_LEN 4096
#define NROWS 16384   // B*S

typedef __attribute__((ext_vector_type(8))) __bf16 bf16x8;
typedef __attribute__((ext_vector_type(8))) unsigned short ushort8;
typedef __attribute__((ext_vector_type(4))) float floatx4;

__device__ __forceinline__ unsigned short f2bf(float f) {   // RNE
    unsigned int u = __float_as_uint(f);
    unsigned int r = (u + 0x7fffu + ((u >> 16) & 1u)) >> 16;
    return (unsigned short)r;
}

__device__ __forceinline__ float fexp2(float x) {
#if __has_builtin(__builtin_amdgcn_exp2f)
    return __builtin_amdgcn_exp2f(x);
#else
    float r; asm("v_exp_f32 %0, %1" : "=v"(r) : "v"(x)); return r;
#endif
}

__device__ __forceinline__ bf16x8 cvt_bf16x8(float4 a, float4 b) {
    union { ushort8 u; bf16x8 v; } r;
    r.u[0] = f2bf(a.x); r.u[1] = f2bf(a.y); r.u[2] = f2bf(a.z); r.u[3] = f2bf(a.w);
    r.u[4] = f2bf(b.x); r.u[5] = f2bf(b.y); r.u[6] = f2bf(b.z); r.u[7] = f2bf(b.w);
    return r.v;
}

// ---------------- K0: weights fp32 -> bf16 transposed (unchanged, proven)
__global__ __launch_bounds__(256) void convw_kernel(
    const float* __restrict__ Wq, const float* __restrict__ Wk,
    const float* __restrict__ Wv, const float* __restrict__ Wo,
    unsigned short* __restrict__ WqT, unsigned short* __restrict__ WkT,
    unsigned short* __restrict__ WvT, unsigned short* __restrict__ WoT)
{
    int tid = blockIdx.x * 256 + threadIdx.x;   // 0..32767
    int n = tid >> 9, k = tid & 511;            // (n<64, k<512)
    WqT[tid] = f2bf(Wq[k * 64 + n]);
    WkT[tid] = f2bf(Wk[k * 64 + n]);
    WvT[tid] = f2bf(Wv[k * 64 + n]);
    int n2 = tid >> 6, k2 = tid & 63;           // (n2<512, k2<64)
    WoT[tid] = f2bf(Wo[k2 * 512 + n2]);
}

// ---------------- K1: fused QKV projection. NEW: K and V are written in
// FRAGMENT-MAJOR layouts so that every MFMA-fragment load in attn is one
// contiguous 1-KB burst (lane-linear), instead of a 16-cache-line gather.
//   KF[grow16][q8 = d/8][cl = s%16][e = d%8]            (1024 u16 per s16)
//   VF[b][kt64][half][u = d/16][cl = d%16][q][e]        (4096 u16 per kt64)
// Q stays row-major (read twice total). Q pre-scaled by log2(e)/64.
__global__ __launch_bounds__(192) void qkv_kernel(
    const float* __restrict__ x,
    const unsigned short* __restrict__ WqT, const unsigned short* __restrict__ WkT,
    const unsigned short* __restrict__ WvT,
    const float* __restrict__ bq, const float* __restrict__ bk, const float* __restrict__ bv,
    unsigned short* __restrict__ Qb, unsigned short* __restrict__ KF,
    unsigned short* __restrict__ VF)
{
    const int row0 = blockIdx.x * 16;
    const int tid = threadIdx.x;
    const int m = tid >> 6;              // wave id: 0=Q, 1=K, 2=V
    const int lane = tid & 63, cl = lane & 15, quad = lane >> 4;
    const unsigned short* WT = (m == 0) ? WqT : (m == 1) ? WkT : WvT;
    const float* bias = (m == 0) ? bq : (m == 1) ? bk : bv;

    floatx4 acc[4];
    #pragma unroll
    for (int t = 0; t < 4; t++) acc[t] = (floatx4){0.f, 0.f, 0.f, 0.f};
    const float* xrow = x + (size_t)(row0 + cl) * 512;
    #pragma unroll 2
    for (int kc = 0; kc < 16; kc++) {
        const int k0 = kc * 32 + quad * 8;
        float4 xa = *(const float4*)(xrow + k0);
        float4 xb = *(const float4*)(xrow + k0 + 4);
        bf16x8 af = cvt_bf16x8(xa, xb);
        #pragma unroll
        for (int t = 0; t < 4; t++) {
            bf16x8 bf = *(const bf16x8*)(const void*)(WT + (t * 16 + cl) * 512 + k0);
            acc[t] = __builtin_amdgcn_mfma_f32_16x16x32_bf16(af, bf, acc[t], 0, 0, 0);
        }
    }
    if (m == 0) {
        const float scl = 0.022542110013890054f;   // log2(e)/64
        #pragma unroll
        for (int t = 0; t < 4; t++) {
            const int d = t * 16 + cl;
            const float bd = bias[d];
            #pragma unroll
            for (int r = 0; r < 4; r++)
                Qb[(size_t)(row0 + quad * 4 + r) * 64 + d] = f2bf((acc[t][r] + bd) * scl);
        }
    } else if (m == 1) {
        // KF: offset = (grow16*8 + d/8)*128 + (s%16)*8 + d%8
        const int g16 = row0 >> 4;
        #pragma unroll
        for (int t = 0; t < 4; t++) {
            const int d = t * 16 + cl;
            const float bd = bias[d];
            const size_t base = ((size_t)g16 * 8 + (d >> 3)) * 128 + (d & 7);
            #pragma unroll
            for (int r = 0; r < 4; r++)
                KF[base + (quad * 4 + r) * 8] = f2bf(acc[t][r] + bd);
        }
    } else {
        // VF: offset = b*S*64 + (s/64)*4096 + ((s/32)&1)*2048 + (d/16)*512
        //            + (d%16)*32 + ((s/8)&3)*8 + s%8
        const int b = row0 >> 12, s_base = row0 & 4095;
        #pragma unroll
        for (int t = 0; t < 4; t++) {
            const int d = t * 16 + cl;
            const float bd = bias[d];
            #pragma unroll
            for (int r = 0; r < 4; r++) {
                const int s = s_base + quad * 4 + r;
                const size_t off = (size_t)b * (S_LEN * 64) + (size_t)(s >> 6) * 4096
                                 + ((s >> 5) & 1) * 2048 + t * 512 + cl * 32
                                 + ((s >> 3) & 3) * 8 + (s & 7);
                VF[off] = f2bf(acc[t][r] + bd);
            }
        }
    }
}

// ---------------- K2: causal flash attention.
// This round (TA/coalescing theory):
//  * K/V loads are lane-linear 1-KB bursts from the fragment-major layouts
//    (was: 16-cache-line gathers; ~256 line-requests per tile per wave --
//    the per-CU address-path cost that was invariant to all prior changes).
//  * 64-row q-block: the 4 waves take 4 q-subtiles and sweep the SAME K/V
//    tiles in lockstep (__syncthreads per strip) -> 4x L1/MSHR reuse, 4x
//    less L2 traffic, and no inter-wave merge (each wave owns its rows).
//  * split-K x4 kept for inventory (grid 1024); max-free softmax; partial
//    sums are plain adds, merged by amerge.
#define PSTR 152   // P-strip row stride (ushorts): 76 dwords -> 2-way bank aliasing (free)
__global__ __launch_bounds__(256, 2) void attn_kernel(
    const unsigned short* __restrict__ Qb, const unsigned short* __restrict__ Kb,
    const unsigned short* __restrict__ Vt,
    float* __restrict__ Po, float* __restrict__ Pl)
{
    __shared__ float4 shraw[4][304];     // per-wave P strip (4864 B each)
    const int bid = blockIdx.x;              // 0..1023
    const int pair = bid >> 2, h = bid & 3;
    const int a = 63 - (pair >> 2);          // q64-tile index, longest-first
    const int b = pair & 3;
    const int q0 = a * 64;
    const int nkt = a + 1;                   // 64-key tiles in causal range
    const int kt0 = (h * nkt) >> 2;          // this block's tile range [kt0,kt1)
    const int kt1 = ((h + 1) * nkt) >> 2;
    const int tid = threadIdx.x;
    const int w = tid >> 6, lane = tid & 63, cl = lane & 15, quad = lane >> 4;

    const size_t qrow = (size_t)b * S_LEN + q0 + w * 16 + cl;
    const bf16x8 aq0 = *(const bf16x8*)(const void*)(Qb + qrow * 64 + quad * 8);
    const bf16x8 aq1 = *(const bf16x8*)(const void*)(Qb + qrow * 64 + 32 + quad * 8);
    const unsigned short* kbb = Kb + (size_t)b * S_LEN * 64;
    const unsigned short* vbb = Vt + (size_t)b * S_LEN * 64;
    const int qm = q0 + w * 16 + quad * 4;   // + r = this lane's q rows (mask)

    float lrow[4];
    floatx4 Oacc[4];
    #pragma unroll
    for (int r = 0; r < 4; r++) lrow[r] = 0.f;
    #pragma unroll
    for (int u = 0; u < 4; u++) Oacc[u] = (floatx4){0.f, 0.f, 0.f, 0.f};

    unsigned short* Pw = (unsigned short*)&shraw[w][0];

    int jt = kt0;
    // -------- 128-key strips: tiles (jt, jt+1), all 4 waves in lockstep ----
    for (; jt + 1 < kt1; jt += 2) {
        __syncthreads();                     // keep waves on the same K/V tiles
        float z[8][4];
        bf16x8 vf[8][2];
        // tile A: K frags (1-KB bursts) + QK
        {
            bf16x8 kf[4][2];
            #pragma unroll
            for (int t = 0; t < 4; t++) {
                const unsigned short* kp = kbb + ((size_t)(jt * 4 + t) * 8 + quad) * 128 + cl * 8;
                kf[t][0] = *(const bf16x8*)(const void*)kp;
                kf[t][1] = *(const bf16x8*)(const void*)(kp + 512);
            }
            #pragma unroll
            for (int t = 0; t < 4; t++) {
                floatx4 acc = (floatx4){0.f, 0.f, 0.f, 0.f};
                acc = __builtin_amdgcn_mfma_f32_16x16x32_bf16(aq0, kf[t][0], acc, 0, 0, 0);
                acc = __builtin_amdgcn_mfma_f32_16x16x32_bf16(aq1, kf[t][1], acc, 0, 0, 0);
                #pragma unroll
                for (int r = 0; r < 4; r++) z[t][r] = acc[r];
            }
        }
        #pragma unroll
        for (int u = 0; u < 4; u++) {
            const unsigned short* vp = vbb + (size_t)jt * 4096 + u * 512 + cl * 32 + quad * 8;
            vf[u][0] = *(const bf16x8*)(const void*)vp;
            vf[u][1] = *(const bf16x8*)(const void*)(vp + 2048);
        }
        // tile B
        {
            bf16x8 kf[4][2];
            #pragma unroll
            for (int t = 0; t < 4; t++) {
                const unsigned short* kp = kbb + ((size_t)((jt + 1) * 4 + t) * 8 + quad) * 128 + cl * 8;
                kf[t][0] = *(const bf16x8*)(const void*)kp;
                kf[t][1] = *(const bf16x8*)(const void*)(kp + 512);
            }
            #pragma unroll
            for (int t = 0; t < 4; t++) {
                floatx4 acc = (floatx4){0.f, 0.f, 0.f, 0.f};
                acc = __builtin_amdgcn_mfma_f32_16x16x32_bf16(aq0, kf[t][0], acc, 0, 0, 0);
                acc = __builtin_amdgcn_mfma_f32_16x16x32_bf16(aq1, kf[t][1], acc, 0, 0, 0);
                #pragma unroll
                for (int r = 0; r < 4; r++) z[4 + t][r] = acc[r];
            }
        }
        #pragma unroll
        for (int u = 0; u < 4; u++) {
            const unsigned short* vp = vbb + (size_t)(jt + 1) * 4096 + u * 512 + cl * 32 + quad * 8;
            vf[4 + u][0] = *(const bf16x8*)(const void*)vp;
            vf[4 + u][1] = *(const bf16x8*)(const void*)(vp + 2048);
        }
        // mask: only the globally-last tile (lives in h=3's range, as tile B)
        if (jt + 1 == nkt - 1) {
            const int j0b = (jt + 1) * 64;
            #pragma unroll
            for (int t = 0; t < 4; t++)
                #pragma unroll
                for (int r = 0; r < 4; r++)
                    if (j0b + t * 16 + cl > qm + r) z[4 + t][r] = -1e30f;
        }
        // direct softmax numerator: p = exp2(z) (max-free, proven)
        #pragma unroll
        for (int t = 0; t < 8; t++)
            #pragma unroll
            for (int r = 0; r < 4; r++) z[t][r] = fexp2(z[t][r]);
        #pragma unroll
        for (int r = 0; r < 4; r++)
            lrow[r] += ((z[0][r] + z[1][r]) + (z[2][r] + z[3][r]))
                     + ((z[4][r] + z[5][r]) + (z[6][r] + z[7][r]));
        // P strip 16x128 -> A-layout via wave-local LDS (compiler inserts waits)
        #pragma unroll
        for (int t = 0; t < 8; t++)
            #pragma unroll
            for (int r = 0; r < 4; r++)
                Pw[(quad * 4 + r) * PSTR + t * 16 + cl] = f2bf(z[t][r]);
        bf16x8 ap0 = *(const bf16x8*)(const void*)(Pw + cl * PSTR + quad * 8);
        bf16x8 ap1 = *(const bf16x8*)(const void*)(Pw + cl * PSTR + 32 + quad * 8);
        bf16x8 ap2 = *(const bf16x8*)(const void*)(Pw + cl * PSTR + 64 + quad * 8);
        bf16x8 ap3 = *(const bf16x8*)(const void*)(Pw + cl * PSTR + 96 + quad * 8);
        #pragma unroll
        for (int u = 0; u < 4; u++) {
            Oacc[u] = __builtin_amdgcn_mfma_f32_16x16x32_bf16(ap0, vf[u][0], Oacc[u], 0, 0, 0);
            Oacc[u] = __builtin_amdgcn_mfma_f32_16x16x32_bf16(ap1, vf[u][1], Oacc[u], 0, 0, 0);
            Oacc[u] = __builtin_amdgcn_mfma_f32_16x16x32_bf16(ap2, vf[4 + u][0], Oacc[u], 0, 0, 0);
            Oacc[u] = __builtin_amdgcn_mfma_f32_16x16x32_bf16(ap3, vf[4 + u][1], Oacc[u], 0, 0, 0);
        }
    }
    // -------- leftover single tile --------
    if (jt < kt1) {
        bf16x8 kf[4][2], vf[4][2];
        #pragma unroll
        for (int t = 0; t < 4; t++) {
            const unsigned short* kp = kbb + ((size_t)(jt * 4 + t) * 8 + quad) * 128 + cl * 8;
            kf[t][0] = *(const bf16x8*)(const void*)kp;
            kf[t][1] = *(const bf16x8*)(const void*)(kp + 512);
        }
        #pragma unroll
        for (int u = 0; u < 4; u++) {
            const unsigned short* vp = vbb + (size_t)jt * 4096 + u * 512 + cl * 32 + quad * 8;
            vf[u][0] = *(const bf16x8*)(const void*)vp;
            vf[u][1] = *(const bf16x8*)(const void*)(vp + 2048);
        }
        float z[4][4];
        #pragma unroll
        for (int t = 0; t < 4; t++) {
            floatx4 acc = (floatx4){0.f, 0.f, 0.f, 0.f};
            acc = __builtin_amdgcn_mfma_f32_16x16x32_bf16(aq0, kf[t][0], acc, 0, 0, 0);
            acc = __builtin_amdgcn_mfma_f32_16x16x32_bf16(aq1, kf[t][1], acc, 0, 0, 0);
            #pragma unroll
            for (int r = 0; r < 4; r++) z[t][r] = acc[r];
        }
        if (jt == nkt - 1) {
            const int j0 = jt * 64;
            #pragma unroll
            for (int t = 0; t < 4; t++)
                #pragma unroll
                for (int r = 0; r < 4; r++)
                    if (j0 + t * 16 + cl > qm + r) z[t][r] = -1e30f;
        }
        #pragma unroll
        for (int t = 0; t < 4; t++)
            #pragma unroll
            for (int r = 0; r < 4; r++) z[t][r] = fexp2(z[t][r]);
        #pragma unroll
        for (int r = 0; r < 4; r++)
            lrow[r] += ((z[0][r] + z[1][r]) + (z[2][r] + z[3][r]));
        #pragma unroll
        for (int t = 0; t < 4; t++)
            #pragma unroll
            for (int r = 0; r < 4; r++)
                Pw[(quad * 4 + r) * PSTR + t * 16 + cl] = f2bf(z[t][r]);
        bf16x8 ap0 = *(const bf16x8*)(const void*)(Pw + cl * PSTR + quad * 8);
        bf16x8 ap1 = *(const bf16x8*)(const void*)(Pw + cl * PSTR + 32 + quad * 8);
        #pragma unroll
        for (int u = 0; u < 4; u++) {
            Oacc[u] = __builtin_amdgcn_mfma_f32_16x16x32_bf16(ap0, vf[u][0], Oacc[u], 0, 0, 0);
            Oacc[u] = __builtin_amdgcn_mfma_f32_16x16x32_bf16(ap1, vf[u][1], Oacc[u], 0, 0, 0);
        }
    }
    // cross-lane l reduce (sum over the 16 col-classes)
    #pragma unroll
    for (int r = 0; r < 4; r++) {
        float s = lrow[r];
        s += __shfl_xor(s, 1, 64);
        s += __shfl_xor(s, 2, 64);
        s += __shfl_xor(s, 4, 64);
        s += __shfl_xor(s, 8, 64);
        lrow[r] = s;
    }
    // each wave owns its 16 rows: write unnormalized partial directly
    {
        float* pob = Po + (size_t)bid * 64 * 64;
        #pragma unroll
        for (int u = 0; u < 4; u++)
            #pragma unroll
            for (int r = 0; r < 4; r++)
                pob[(size_t)(w * 16 + quad * 4 + r) * 64 + u * 16 + cl] = Oacc[u][r];
        if (cl == 0) {
            #pragma unroll
            for (int r = 0; r < 4; r++)
                Pl[(size_t)bid * 64 + w * 16 + quad * 4 + r] = lrow[r];
        }
    }
}

// ---------------- K2b: sum the 4 split-K partials -> normalized bf16 Ob
__global__ __launch_bounds__(256) void amerge_kernel(
    const float* __restrict__ Po, const float* __restrict__ Pl,
    unsigned short* __restrict__ Ob)
{
    const int pair = blockIdx.x;             // 0..255
    const int a = 63 - (pair >> 2), b = pair & 3;
    const int tid = threadIdx.x;
    const int d0 = (tid & 15) * 4, r0 = tid >> 4;
    const size_t base = (size_t)pair * 4;
    #pragma unroll
    for (int rr = 0; rr < 4; rr++) {
        const int row = r0 + rr * 16;        // 0..63
        const float L = Pl[(base + 0) * 64 + row] + Pl[(base + 1) * 64 + row]
                      + Pl[(base + 2) * 64 + row] + Pl[(base + 3) * 64 + row];
        const float invL = 1.0f / L;
        const float4 a0 = *(const float4*)(Po + ((base + 0) * 64 + row) * 64 + d0);
        const float4 a1 = *(const float4*)(Po + ((base + 1) * 64 + row) * 64 + d0);
        const float4 a2 = *(const float4*)(Po + ((base + 2) * 64 + row) * 64 + d0);
        const float4 a3 = *(const float4*)(Po + ((base + 3) * 64 + row) * 64 + d0);
        unsigned short ov[4];
        ov[0] = f2bf((a0.x + a1.x + a2.x + a3.x) * invL);
        ov[1] = f2bf((a0.y + a1.y + a2.y + a3.y) * invL);
        ov[2] = f2bf((a0.z + a1.z + a2.z + a3.z) * invL);
        ov[3] = f2bf((a0.w + a1.w + a2.w + a3.w) * invL);
        *(uint2*)(void*)(Ob + ((size_t)b * S_LEN + a * 64 + row) * 64 + d0) = *(const uint2*)ov;
    }
}

// ---------------- K3: out = O @ Wo + bo via MFMA (unchanged, proven)
__global__ __launch_bounds__(256) void oproj_kernel(
    const unsigned short* __restrict__ Ob, const unsigned short* __restrict__ WoT,
    const float* __restrict__ bo, float* __restrict__ out)
{
    const int row0 = blockIdx.x * 16;
    const int tid = threadIdx.x;
    const int w = tid >> 6, lane = tid & 63, cl = lane & 15, quad = lane >> 4;
    const unsigned short* op = Ob + (size_t)(row0 + cl) * 64 + quad * 8;
    const bf16x8 a0 = *(const bf16x8*)(const void*)op;
    const bf16x8 a1 = *(const bf16x8*)(const void*)(op + 32);
    #pragma unroll 2
    for (int i = 0; i < 8; i++) {
        const int n = w * 128 + i * 16 + cl;
        const unsigned short* wp = WoT + (size_t)n * 64 + quad * 8;
        bf16x8 b0 = *(const bf16x8*)(const void*)wp;
        bf16x8 b1 = *(const bf16x8*)(const void*)(wp + 32);
        floatx4 acc = (floatx4){0.f, 0.f, 0.f, 0.f};
        acc = __builtin_amdgcn_mfma_f32_16x16x32_bf16(a0, b0, acc, 0, 0, 0);
        acc = __builtin_amdgcn_mfma_f32_16x16x32_bf16(a1, b1, acc, 0, 0, 0);
        const float bod = bo[n];
        #pragma unroll
        for (int r = 0; r < 4; r++)
            out[(size_t)(row0 + quad * 4 + r) * 512 + n] = acc[r] + bod;
    }
}

extern "C" void kernel_launch(void* const* d_in, const int* in_sizes, int n_in,
                              void* d_out, int out_size, void* d_ws, size_t ws_size,
                              hipStream_t stream) {
    const float* x  = (const float*)d_in[0];
    const float* Wq = (const float*)d_in[1];
    const float* bq = (const float*)d_in[2];
    const float* Wk = (const float*)d_in[3];
    const float* bk = (const float*)d_in[4];
    const float* Wv = (const float*)d_in[5];
    const float* bv = (const float*)d_in[6];
    const float* Wo = (const float*)d_in[7];
    const float* bo = (const float*)d_in[8];
    float* out = (float*)d_out;

    unsigned short* Qb  = (unsigned short*)d_ws;               // 2 MB
    unsigned short* KF  = Qb + (size_t)NROWS * 64;             // 2 MB (fragment-major)
    unsigned short* VF  = KF + (size_t)NROWS * 64;             // 2 MB (fragment-major)
    unsigned short* Ob  = VF + (size_t)NROWS * 64;             // 2 MB (bf16 O, row-major)
    unsigned short* WqT = Ob + (size_t)NROWS * 64;             // 64 KB each
    unsigned short* WkT = WqT + 512 * 64;
    unsigned short* WvT = WkT + 512 * 64;
    unsigned short* WoT = WvT + 512 * 64;
    float* Pl = (float*)(WoT + 512 * 64);                      // 1024*64 f32 = 256 KB
    // Po partials live in d_out (16.8 MB < 33.5 MB); oproj overwrites out after.
    float* Po = out;

    convw_kernel<<<128, 256, 0, stream>>>(Wq, Wk, Wv, Wo, WqT, WkT, WvT, WoT);
    qkv_kernel<<<1024, 192, 0, stream>>>(x, WqT, WkT, WvT, bq, bk, bv, Qb, KF, VF);
    attn_kernel<<<1024, 256, 0, stream>>>(Qb, KF, VF, Po, Pl);
    amerge_kernel<<<256, 256, 0, stream>>>(Po, Pl, Ob);
    oproj_kernel<<<NROWS / 16, 256, 0, stream>>>(Ob, WoT, bo, out);
}

// Round 8
// 151.364 us; speedup vs baseline: 1.3952x; 1.1386x over previous
//
#include <hip/hip_runtime.h>

#define S_LEN 4096
#define NROWS 16384   // B*S

typedef __attribute__((ext_vector_type(8))) __bf16 bf16x8;
typedef __attribute__((ext_vector_type(8))) unsigned short ushort8;
typedef __attribute__((ext_vector_type(4))) unsigned short ushort4_t;
typedef __attribute__((ext_vector_type(4))) float floatx4;

__device__ __forceinline__ unsigned short f2bf(float f) {   // RNE
    unsigned int u = __float_as_uint(f);
    unsigned int r = (u + 0x7fffu + ((u >> 16) & 1u)) >> 16;
    return (unsigned short)r;
}

__device__ __forceinline__ float fexp2(float x) {
#if __has_builtin(__builtin_amdgcn_exp2f)
    return __builtin_amdgcn_exp2f(x);
#else
    float r; asm("v_exp_f32 %0, %1" : "=v"(r) : "v"(x)); return r;
#endif
}

// ---------------- K0: weights fp32 -> bf16 FRAGMENT-MAJOR buffers.
// WqF/WkF/WvF: B-frag for (t,kc) of qkv's MFMA:
//   idx = (t*16+kc)*512 + (quad*16+cl)*8 + e  <-  W[k=kc*32+quad*8+e][n=t*16+cl]
// WoF: B-frag for (g,h) of oproj:
//   idx = (g*2+h)*512 + (quad*16+cl)*8 + e    <-  Wo[k=h*32+quad*8+e][n=g*16+cl]
// Every consumer load is a lane-linear 1-KB burst.
__global__ __launch_bounds__(256) void convw_kernel(
    const float* __restrict__ Wq, const float* __restrict__ Wk,
    const float* __restrict__ Wv, const float* __restrict__ Wo,
    unsigned short* __restrict__ WqF, unsigned short* __restrict__ WkF,
    unsigned short* __restrict__ WvF, unsigned short* __restrict__ WoF)
{
    int tid = blockIdx.x * 256 + threadIdx.x;   // 0..32767
    {
        const int e = tid & 7, cl = (tid >> 3) & 15, quad = (tid >> 7) & 3;
        const int kc = (tid >> 9) & 15, t = tid >> 13;
        const int n = t * 16 + cl, k = kc * 32 + quad * 8 + e;
        WqF[tid] = f2bf(Wq[k * 64 + n]);
        WkF[tid] = f2bf(Wk[k * 64 + n]);
        WvF[tid] = f2bf(Wv[k * 64 + n]);
    }
    {
        const int e = tid & 7, cl = (tid >> 3) & 15, quad = (tid >> 7) & 3;
        const int h = (tid >> 9) & 1, g = tid >> 10;
        const int n = g * 16 + cl, k = h * 32 + quad * 8 + e;
        WoF[tid] = f2bf(Wo[k * 512 + n]);
    }
}

// ---------------- K1: fused QKV projection, fully coalesced.
// x tile (16 rows x 512 f32) staged into LDS as bf16 A-fragments via
// coalesced float4 reads; per-kc fragment block is 512 elements:
//   xs[kc*512 + quad*128 + cl*8 + e] = x[row0+cl][kc*32+quad*8+e]
// (R7 bug: stride was 1024 -> 16 KB OOB on xs[8192]; fixed to 512.)
// Weights from fragment-major WqF/WkF/WvF (1-KB bursts).
__global__ __launch_bounds__(192) void qkv_kernel(
    const float* __restrict__ x,
    const unsigned short* __restrict__ WqF, const unsigned short* __restrict__ WkF,
    const unsigned short* __restrict__ WvF,
    const float* __restrict__ bq, const float* __restrict__ bk, const float* __restrict__ bv,
    unsigned short* __restrict__ Qb, unsigned short* __restrict__ KF,
    unsigned short* __restrict__ VF)
{
    __shared__ unsigned short xs[8192];  // 16 KB: x tile bf16, A-frag layout
    const int row0 = blockIdx.x * 16;
    const int tid = threadIdx.x;

    // stage: xs[(k>>5)*512 + ((k>>3)&3)*128 + r*8 + (k&7)] = x[row0+r][k]
    const float* xt = x + (size_t)row0 * 512;
    for (int i = tid; i < 2048; i += 192) {
        float4 v = *(const float4*)(xt + i * 4);
        const int r = i >> 7, k = (i & 127) * 4;
        ushort4_t o;
        o[0] = f2bf(v.x); o[1] = f2bf(v.y); o[2] = f2bf(v.z); o[3] = f2bf(v.w);
        *(ushort4_t*)(xs + (k >> 5) * 512 + ((k >> 3) & 3) * 128 + r * 8 + (k & 7)) = o;
    }
    __syncthreads();

    const int m = tid >> 6;              // wave id: 0=Q, 1=K, 2=V
    const int lane = tid & 63, cl = lane & 15, quad = lane >> 4;
    const unsigned short* WF = (m == 0) ? WqF : (m == 1) ? WkF : WvF;
    const float* bias = (m == 0) ? bq : (m == 1) ? bk : bv;

    floatx4 acc[4];
    #pragma unroll
    for (int t = 0; t < 4; t++) acc[t] = (floatx4){0.f, 0.f, 0.f, 0.f};
    #pragma unroll 2
    for (int kc = 0; kc < 16; kc++) {
        const bf16x8 af = *(const bf16x8*)(const void*)(xs + kc * 512 + lane * 8);
        #pragma unroll
        for (int t = 0; t < 4; t++) {
            const bf16x8 bf = *(const bf16x8*)(const void*)(WF + (size_t)(t * 16 + kc) * 512 + lane * 8);
            acc[t] = __builtin_amdgcn_mfma_f32_16x16x32_bf16(af, bf, acc[t], 0, 0, 0);
        }
    }
    if (m == 0) {
        const float scl = 0.022542110013890054f;   // log2(e)/64
        #pragma unroll
        for (int t = 0; t < 4; t++) {
            const int d = t * 16 + cl;
            const float bd = bias[d];
            #pragma unroll
            for (int r = 0; r < 4; r++)
                Qb[(size_t)(row0 + quad * 4 + r) * 64 + d] = f2bf((acc[t][r] + bd) * scl);
        }
    } else if (m == 1) {
        const int g16 = row0 >> 4;
        #pragma unroll
        for (int t = 0; t < 4; t++) {
            const int d = t * 16 + cl;
            const float bd = bias[d];
            const size_t base = ((size_t)g16 * 8 + (d >> 3)) * 128 + (d & 7);
            #pragma unroll
            for (int r = 0; r < 4; r++)
                KF[base + (quad * 4 + r) * 8] = f2bf(acc[t][r] + bd);
        }
    } else {
        const int b = row0 >> 12, s_base = row0 & 4095;
        #pragma unroll
        for (int t = 0; t < 4; t++) {
            const int d = t * 16 + cl;
            const float bd = bias[d];
            #pragma unroll
            for (int r = 0; r < 4; r++) {
                const int s = s_base + quad * 4 + r;
                const size_t off = (size_t)b * (S_LEN * 64) + (size_t)(s >> 6) * 4096
                                 + ((s >> 5) & 1) * 2048 + t * 512 + cl * 32
                                 + ((s >> 3) & 3) * 8 + (s & 7);
                VF[off] = f2bf(acc[t][r] + bd);
            }
        }
    }
}

// ---------------- K2: causal flash attention (unchanged from R6, proven:
// fragment-major 1-KB-burst K/V loads, 64-row lockstep q-blocks, max-free
// softmax, split-K x4 with plain-sum partials).
#define PSTR 152
__global__ __launch_bounds__(256, 2) void attn_kernel(
    const unsigned short* __restrict__ Qb, const unsigned short* __restrict__ Kb,
    const unsigned short* __restrict__ Vt,
    float* __restrict__ Po, float* __restrict__ Pl)
{
    __shared__ float4 shraw[4][304];
    const int bid = blockIdx.x;              // 0..1023
    const int pair = bid >> 2, h = bid & 3;
    const int a = 63 - (pair >> 2);
    const int b = pair & 3;
    const int q0 = a * 64;
    const int nkt = a + 1;
    const int kt0 = (h * nkt) >> 2;
    const int kt1 = ((h + 1) * nkt) >> 2;
    const int tid = threadIdx.x;
    const int w = tid >> 6, lane = tid & 63, cl = lane & 15, quad = lane >> 4;

    const size_t qrow = (size_t)b * S_LEN + q0 + w * 16 + cl;
    const bf16x8 aq0 = *(const bf16x8*)(const void*)(Qb + qrow * 64 + quad * 8);
    const bf16x8 aq1 = *(const bf16x8*)(const void*)(Qb + qrow * 64 + 32 + quad * 8);
    const unsigned short* kbb = Kb + (size_t)b * S_LEN * 64;
    const unsigned short* vbb = Vt + (size_t)b * S_LEN * 64;
    const int qm = q0 + w * 16 + quad * 4;

    float lrow[4];
    floatx4 Oacc[4];
    #pragma unroll
    for (int r = 0; r < 4; r++) lrow[r] = 0.f;
    #pragma unroll
    for (int u = 0; u < 4; u++) Oacc[u] = (floatx4){0.f, 0.f, 0.f, 0.f};

    unsigned short* Pw = (unsigned short*)&shraw[w][0];

    int jt = kt0;
    for (; jt + 1 < kt1; jt += 2) {
        __syncthreads();
        float z[8][4];
        bf16x8 vf[8][2];
        {
            bf16x8 kf[4][2];
            #pragma unroll
            for (int t = 0; t < 4; t++) {
                const unsigned short* kp = kbb + ((size_t)(jt * 4 + t) * 8 + quad) * 128 + cl * 8;
                kf[t][0] = *(const bf16x8*)(const void*)kp;
                kf[t][1] = *(const bf16x8*)(const void*)(kp + 512);
            }
            #pragma unroll
            for (int t = 0; t < 4; t++) {
                floatx4 acc = (floatx4){0.f, 0.f, 0.f, 0.f};
                acc = __builtin_amdgcn_mfma_f32_16x16x32_bf16(aq0, kf[t][0], acc, 0, 0, 0);
                acc = __builtin_amdgcn_mfma_f32_16x16x32_bf16(aq1, kf[t][1], acc, 0, 0, 0);
                #pragma unroll
                for (int r = 0; r < 4; r++) z[t][r] = acc[r];
            }
        }
        #pragma unroll
        for (int u = 0; u < 4; u++) {
            const unsigned short* vp = vbb + (size_t)jt * 4096 + u * 512 + cl * 32 + quad * 8;
            vf[u][0] = *(const bf16x8*)(const void*)vp;
            vf[u][1] = *(const bf16x8*)(const void*)(vp + 2048);
        }
        {
            bf16x8 kf[4][2];
            #pragma unroll
            for (int t = 0; t < 4; t++) {
                const unsigned short* kp = kbb + ((size_t)((jt + 1) * 4 + t) * 8 + quad) * 128 + cl * 8;
                kf[t][0] = *(const bf16x8*)(const void*)kp;
                kf[t][1] = *(const bf16x8*)(const void*)(kp + 512);
            }
            #pragma unroll
            for (int t = 0; t < 4; t++) {
                floatx4 acc = (floatx4){0.f, 0.f, 0.f, 0.f};
                acc = __builtin_amdgcn_mfma_f32_16x16x32_bf16(aq0, kf[t][0], acc, 0, 0, 0);
                acc = __builtin_amdgcn_mfma_f32_16x16x32_bf16(aq1, kf[t][1], acc, 0, 0, 0);
                #pragma unroll
                for (int r = 0; r < 4; r++) z[4 + t][r] = acc[r];
            }
        }
        #pragma unroll
        for (int u = 0; u < 4; u++) {
            const unsigned short* vp = vbb + (size_t)(jt + 1) * 4096 + u * 512 + cl * 32 + quad * 8;
            vf[4 + u][0] = *(const bf16x8*)(const void*)vp;
            vf[4 + u][1] = *(const bf16x8*)(const void*)(vp + 2048);
        }
        if (jt + 1 == nkt - 1) {
            const int j0b = (jt + 1) * 64;
            #pragma unroll
            for (int t = 0; t < 4; t++)
                #pragma unroll
                for (int r = 0; r < 4; r++)
                    if (j0b + t * 16 + cl > qm + r) z[4 + t][r] = -1e30f;
        }
        #pragma unroll
        for (int t = 0; t < 8; t++)
            #pragma unroll
            for (int r = 0; r < 4; r++) z[t][r] = fexp2(z[t][r]);
        #pragma unroll
        for (int r = 0; r < 4; r++)
            lrow[r] += ((z[0][r] + z[1][r]) + (z[2][r] + z[3][r]))
                     + ((z[4][r] + z[5][r]) + (z[6][r] + z[7][r]));
        #pragma unroll
        for (int t = 0; t < 8; t++)
            #pragma unroll
            for (int r = 0; r < 4; r++)
                Pw[(quad * 4 + r) * PSTR + t * 16 + cl] = f2bf(z[t][r]);
        bf16x8 ap0 = *(const bf16x8*)(const void*)(Pw + cl * PSTR + quad * 8);
        bf16x8 ap1 = *(const bf16x8*)(const void*)(Pw + cl * PSTR + 32 + quad * 8);
        bf16x8 ap2 = *(const bf16x8*)(const void*)(Pw + cl * PSTR + 64 + quad * 8);
        bf16x8 ap3 = *(const bf16x8*)(const void*)(Pw + cl * PSTR + 96 + quad * 8);
        #pragma unroll
        for (int u = 0; u < 4; u++) {
            Oacc[u] = __builtin_amdgcn_mfma_f32_16x16x32_bf16(ap0, vf[u][0], Oacc[u], 0, 0, 0);
            Oacc[u] = __builtin_amdgcn_mfma_f32_16x16x32_bf16(ap1, vf[u][1], Oacc[u], 0, 0, 0);
            Oacc[u] = __builtin_amdgcn_mfma_f32_16x16x32_bf16(ap2, vf[4 + u][0], Oacc[u], 0, 0, 0);
            Oacc[u] = __builtin_amdgcn_mfma_f32_16x16x32_bf16(ap3, vf[4 + u][1], Oacc[u], 0, 0, 0);
        }
    }
    if (jt < kt1) {
        bf16x8 kf[4][2], vf[4][2];
        #pragma unroll
        for (int t = 0; t < 4; t++) {
            const unsigned short* kp = kbb + ((size_t)(jt * 4 + t) * 8 + quad) * 128 + cl * 8;
            kf[t][0] = *(const bf16x8*)(const void*)kp;
            kf[t][1] = *(const bf16x8*)(const void*)(kp + 512);
        }
        #pragma unroll
        for (int u = 0; u < 4; u++) {
            const unsigned short* vp = vbb + (size_t)jt * 4096 + u * 512 + cl * 32 + quad * 8;
            vf[u][0] = *(const bf16x8*)(const void*)vp;
            vf[u][1] = *(const bf16x8*)(const void*)(vp + 2048);
        }
        float z[4][4];
        #pragma unroll
        for (int t = 0; t < 4; t++) {
            floatx4 acc = (floatx4){0.f, 0.f, 0.f, 0.f};
            acc = __builtin_amdgcn_mfma_f32_16x16x32_bf16(aq0, kf[t][0], acc, 0, 0, 0);
            acc = __builtin_amdgcn_mfma_f32_16x16x32_bf16(aq1, kf[t][1], acc, 0, 0, 0);
            #pragma unroll
            for (int r = 0; r < 4; r++) z[t][r] = acc[r];
        }
        if (jt == nkt - 1) {
            const int j0 = jt * 64;
            #pragma unroll
            for (int t = 0; t < 4; t++)
                #pragma unroll
                for (int r = 0; r < 4; r++)
                    if (j0 + t * 16 + cl > qm + r) z[t][r] = -1e30f;
        }
        #pragma unroll
        for (int t = 0; t < 4; t++)
            #pragma unroll
            for (int r = 0; r < 4; r++) z[t][r] = fexp2(z[t][r]);
        #pragma unroll
        for (int r = 0; r < 4; r++)
            lrow[r] += ((z[0][r] + z[1][r]) + (z[2][r] + z[3][r]));
        #pragma unroll
        for (int t = 0; t < 4; t++)
            #pragma unroll
            for (int r = 0; r < 4; r++)
                Pw[(quad * 4 + r) * PSTR + t * 16 + cl] = f2bf(z[t][r]);
        bf16x8 ap0 = *(const bf16x8*)(const void*)(Pw + cl * PSTR + quad * 8);
        bf16x8 ap1 = *(const bf16x8*)(const void*)(Pw + cl * PSTR + 32 + quad * 8);
        #pragma unroll
        for (int u = 0; u < 4; u++) {
            Oacc[u] = __builtin_amdgcn_mfma_f32_16x16x32_bf16(ap0, vf[u][0], Oacc[u], 0, 0, 0);
            Oacc[u] = __builtin_amdgcn_mfma_f32_16x16x32_bf16(ap1, vf[u][1], Oacc[u], 0, 0, 0);
        }
    }
    #pragma unroll
    for (int r = 0; r < 4; r++) {
        float s = lrow[r];
        s += __shfl_xor(s, 1, 64);
        s += __shfl_xor(s, 2, 64);
        s += __shfl_xor(s, 4, 64);
        s += __shfl_xor(s, 8, 64);
        lrow[r] = s;
    }
    {
        float* pob = Po + (size_t)bid * 64 * 64;
        #pragma unroll
        for (int u = 0; u < 4; u++)
            #pragma unroll
            for (int r = 0; r < 4; r++)
                pob[(size_t)(w * 16 + quad * 4 + r) * 64 + u * 16 + cl] = Oacc[u][r];
        if (cl == 0) {
            #pragma unroll
            for (int r = 0; r < 4; r++)
                Pl[(size_t)bid * 64 + w * 16 + quad * 4 + r] = lrow[r];
        }
    }
}

// ---------------- K2b: sum split-K partials -> normalized FRAGMENT-MAJOR
// bf16 ObF, so oproj's A-loads are 1-KB bursts:
//   ObF[(blk16*2 + d/32)*512 + ((d>>3)&3)*128 + (row%16)*8 + d%8] = O[row][d]
__global__ __launch_bounds__(256) void amerge_kernel(
    const float* __restrict__ Po, const float* __restrict__ Pl,
    unsigned short* __restrict__ ObF)
{
    const int pair = blockIdx.x;             // 0..255
    const int a = 63 - (pair >> 2), b = pair & 3;
    const int tid = threadIdx.x;
    const int d0 = (tid & 15) * 4, r0 = tid >> 4;
    const size_t base = (size_t)pair * 4;
    const int h2 = d0 >> 5, qd = (d0 >> 3) & 3, e0 = d0 & 7;
    #pragma unroll
    for (int rr = 0; rr < 4; rr++) {
        const int row = r0 + rr * 16;        // 0..63 within the a-tile
        const float L = Pl[(base + 0) * 64 + row] + Pl[(base + 1) * 64 + row]
                      + Pl[(base + 2) * 64 + row] + Pl[(base + 3) * 64 + row];
        const float invL = 1.0f / L;
        const float4 a0 = *(const float4*)(Po + ((base + 0) * 64 + row) * 64 + d0);
        const float4 a1 = *(const float4*)(Po + ((base + 1) * 64 + row) * 64 + d0);
        const float4 a2 = *(const float4*)(Po + ((base + 2) * 64 + row) * 64 + d0);
        const float4 a3 = *(const float4*)(Po + ((base + 3) * 64 + row) * 64 + d0);
        ushort4_t ov;
        ov[0] = f2bf((a0.x + a1.x + a2.x + a3.x) * invL);
        ov[1] = f2bf((a0.y + a1.y + a2.y + a3.y) * invL);
        ov[2] = f2bf((a0.z + a1.z + a2.z + a3.z) * invL);
        ov[3] = f2bf((a0.w + a1.w + a2.w + a3.w) * invL);
        const int blk16 = b * 256 + a * 4 + (row >> 4);
        const size_t idx = (size_t)(blk16 * 2 + h2) * 512 + (qd * 16 + (row & 15)) * 8 + e0;
        *(ushort4_t*)(ObF + idx) = ov;
    }
}

// ---------------- K3: out = O @ Wo + bo; all loads 1-KB bursts
// (A from fragment-major ObF, B from fragment-major WoF).
__global__ __launch_bounds__(256) void oproj_kernel(
    const unsigned short* __restrict__ ObF, const unsigned short* __restrict__ WoF,
    const float* __restrict__ bo, float* __restrict__ out)
{
    const int blk = blockIdx.x;              // 16-row block
    const int row0 = blk * 16;
    const int tid = threadIdx.x;
    const int w = tid >> 6, lane = tid & 63, cl = lane & 15, quad = lane >> 4;
    const bf16x8 a0 = *(const bf16x8*)(const void*)(ObF + (size_t)(blk * 2 + 0) * 512 + lane * 8);
    const bf16x8 a1 = *(const bf16x8*)(const void*)(ObF + (size_t)(blk * 2 + 1) * 512 + lane * 8);
    #pragma unroll 2
    for (int i = 0; i < 8; i++) {
        const int g = w * 8 + i;
        const int n = g * 16 + cl;
        bf16x8 b0 = *(const bf16x8*)(const void*)(WoF + (size_t)(g * 2 + 0) * 512 + lane * 8);
        bf16x8 b1 = *(const bf16x8*)(const void*)(WoF + (size_t)(g * 2 + 1) * 512 + lane * 8);
        floatx4 acc = (floatx4){0.f, 0.f, 0.f, 0.f};
        acc = __builtin_amdgcn_mfma_f32_16x16x32_bf16(a0, b0, acc, 0, 0, 0);
        acc = __builtin_amdgcn_mfma_f32_16x16x32_bf16(a1, b1, acc, 0, 0, 0);
        const float bod = bo[n];
        #pragma unroll
        for (int r = 0; r < 4; r++)
            out[(size_t)(row0 + quad * 4 + r) * 512 + n] = acc[r] + bod;
    }
}

extern "C" void kernel_launch(void* const* d_in, const int* in_sizes, int n_in,
                              void* d_out, int out_size, void* d_ws, size_t ws_size,
                              hipStream_t stream) {
    const float* x  = (const float*)d_in[0];
    const float* Wq = (const float*)d_in[1];
    const float* bq = (const float*)d_in[2];
    const float* Wk = (const float*)d_in[3];
    const float* bk = (const float*)d_in[4];
    const float* Wv = (const float*)d_in[5];
    const float* bv = (const float*)d_in[6];
    const float* Wo = (const float*)d_in[7];
    const float* bo = (const float*)d_in[8];
    float* out = (float*)d_out;

    unsigned short* Qb  = (unsigned short*)d_ws;               // 2 MB
    unsigned short* KF  = Qb + (size_t)NROWS * 64;             // 2 MB (fragment-major)
    unsigned short* VF  = KF + (size_t)NROWS * 64;             // 2 MB (fragment-major)
    unsigned short* ObF = VF + (size_t)NROWS * 64;             // 2 MB (fragment-major)
    unsigned short* WqF = ObF + (size_t)NROWS * 64;            // 64 KB each
    unsigned short* WkF = WqF + 512 * 64;
    unsigned short* WvF = WkF + 512 * 64;
    unsigned short* WoF = WvF + 512 * 64;
    float* Pl = (float*)(WoF + 512 * 64);                      // 1024*64 f32 = 256 KB
    // Po partials live in d_out (16.8 MB < 33.5 MB); oproj overwrites out after.
    float* Po = out;

    convw_kernel<<<128, 256, 0, stream>>>(Wq, Wk, Wv, Wo, WqF, WkF, WvF, WoF);
    qkv_kernel<<<1024, 192, 0, stream>>>(x, WqF, WkF, WvF, bq, bk, bv, Qb, KF, VF);
    attn_kernel<<<1024, 256, 0, stream>>>(Qb, KF, VF, Po, Pl);
    amerge_kernel<<<256, 256, 0, stream>>>(Po, Pl, ObF);
    oproj_kernel<<<NROWS / 16, 256, 0, stream>>>(ObF, WoF, bo, out);
}

// Round 9
// 145.635 us; speedup vs baseline: 1.4501x; 1.0393x over previous
//
#include <hip/hip_runtime.h>

#define S_LEN 4096
#define NROWS 16384   // B*S

typedef __attribute__((ext_vector_type(8))) __bf16 bf16x8;
typedef __attribute__((ext_vector_type(8))) unsigned short ushort8;
typedef __attribute__((ext_vector_type(4))) unsigned short ushort4_t;
typedef __attribute__((ext_vector_type(4))) float floatx4;

// Native RTNE f32->bf16 (compiler emits v_cvt_pk_bf16_f32 for pairs; the
// old manual bit-RNE was ~4 VALU/elem and unfusable -- m240 evidence).
__device__ __forceinline__ unsigned short f2bf(float f) {
    union { __bf16 h; unsigned short u; } c;
    c.h = (__bf16)f;
    return c.u;
}

__device__ __forceinline__ float fexp2(float x) {
#if __has_builtin(__builtin_amdgcn_exp2f)
    return __builtin_amdgcn_exp2f(x);
#else
    float r; asm("v_exp_f32 %0, %1" : "=v"(r) : "v"(x)); return r;
#endif
}

__device__ __forceinline__ bf16x8 cvt_bf16x8(float4 a, float4 b) {
    bf16x8 v;
    v[0] = (__bf16)a.x; v[1] = (__bf16)a.y; v[2] = (__bf16)a.z; v[3] = (__bf16)a.w;
    v[4] = (__bf16)b.x; v[5] = (__bf16)b.y; v[6] = (__bf16)b.z; v[7] = (__bf16)b.w;
    return v;
}

// ---------------- K0: weights fp32 -> bf16 FRAGMENT-MAJOR buffers (proven).
__global__ __launch_bounds__(256) void convw_kernel(
    const float* __restrict__ Wq, const float* __restrict__ Wk,
    const float* __restrict__ Wv, const float* __restrict__ Wo,
    unsigned short* __restrict__ WqF, unsigned short* __restrict__ WkF,
    unsigned short* __restrict__ WvF, unsigned short* __restrict__ WoF)
{
    int tid = blockIdx.x * 256 + threadIdx.x;   // 0..32767
    {
        const int e = tid & 7, cl = (tid >> 3) & 15, quad = (tid >> 7) & 3;
        const int kc = (tid >> 9) & 15, t = tid >> 13;
        const int n = t * 16 + cl, k = kc * 32 + quad * 8 + e;
        WqF[tid] = f2bf(Wq[k * 64 + n]);
        WkF[tid] = f2bf(Wk[k * 64 + n]);
        WvF[tid] = f2bf(Wv[k * 64 + n]);
    }
    {
        const int e = tid & 7, cl = (tid >> 3) & 15, quad = (tid >> 7) & 3;
        const int h = (tid >> 9) & 1, g = tid >> 10;
        const int n = g * 16 + cl, k = h * 32 + quad * 8 + e;
        WoF[tid] = f2bf(Wo[k * 512 + n]);
    }
}

// ---------------- K1: fused QKV projection, fully coalesced (proven R8).
__global__ __launch_bounds__(192) void qkv_kernel(
    const float* __restrict__ x,
    const unsigned short* __restrict__ WqF, const unsigned short* __restrict__ WkF,
    const unsigned short* __restrict__ WvF,
    const float* __restrict__ bq, const float* __restrict__ bk, const float* __restrict__ bv,
    unsigned short* __restrict__ Qb, unsigned short* __restrict__ KF,
    unsigned short* __restrict__ VF)
{
    __shared__ unsigned short xs[8192];  // 16 KB: x tile bf16, A-frag layout
    const int row0 = blockIdx.x * 16;
    const int tid = threadIdx.x;

    // stage: xs[(k>>5)*512 + ((k>>3)&3)*128 + r*8 + (k&7)] = x[row0+r][k]
    const float* xt = x + (size_t)row0 * 512;
    for (int i = tid; i < 2048; i += 192) {
        float4 v = *(const float4*)(xt + i * 4);
        const int r = i >> 7, k = (i & 127) * 4;
        ushort4_t o;
        o[0] = f2bf(v.x); o[1] = f2bf(v.y); o[2] = f2bf(v.z); o[3] = f2bf(v.w);
        *(ushort4_t*)(xs + (k >> 5) * 512 + ((k >> 3) & 3) * 128 + r * 8 + (k & 7)) = o;
    }
    __syncthreads();

    const int m = tid >> 6;              // wave id: 0=Q, 1=K, 2=V
    const int lane = tid & 63, cl = lane & 15, quad = lane >> 4;
    const unsigned short* WF = (m == 0) ? WqF : (m == 1) ? WkF : WvF;
    const float* bias = (m == 0) ? bq : (m == 1) ? bk : bv;

    floatx4 acc[4];
    #pragma unroll
    for (int t = 0; t < 4; t++) acc[t] = (floatx4){0.f, 0.f, 0.f, 0.f};
    #pragma unroll 2
    for (int kc = 0; kc < 16; kc++) {
        const bf16x8 af = *(const bf16x8*)(const void*)(xs + kc * 512 + lane * 8);
        #pragma unroll
        for (int t = 0; t < 4; t++) {
            const bf16x8 bf = *(const bf16x8*)(const void*)(WF + (size_t)(t * 16 + kc) * 512 + lane * 8);
            acc[t] = __builtin_amdgcn_mfma_f32_16x16x32_bf16(af, bf, acc[t], 0, 0, 0);
        }
    }
    if (m == 0) {
        const float scl = 0.022542110013890054f;   // log2(e)/64
        #pragma unroll
        for (int t = 0; t < 4; t++) {
            const int d = t * 16 + cl;
            const float bd = bias[d];
            #pragma unroll
            for (int r = 0; r < 4; r++)
                Qb[(size_t)(row0 + quad * 4 + r) * 64 + d] = f2bf((acc[t][r] + bd) * scl);
        }
    } else if (m == 1) {
        const int g16 = row0 >> 4;
        #pragma unroll
        for (int t = 0; t < 4; t++) {
            const int d = t * 16 + cl;
            const float bd = bias[d];
            const size_t base = ((size_t)g16 * 8 + (d >> 3)) * 128 + (d & 7);
            #pragma unroll
            for (int r = 0; r < 4; r++)
                KF[base + (quad * 4 + r) * 8] = f2bf(acc[t][r] + bd);
        }
    } else {
        const int b = row0 >> 12, s_base = row0 & 4095;
        #pragma unroll
        for (int t = 0; t < 4; t++) {
            const int d = t * 16 + cl;
            const float bd = bias[d];
            #pragma unroll
            for (int r = 0; r < 4; r++) {
                const int s = s_base + quad * 4 + r;
                const size_t off = (size_t)b * (S_LEN * 64) + (size_t)(s >> 6) * 4096
                                 + ((s >> 5) & 1) * 2048 + t * 512 + cl * 32
                                 + ((s >> 3) & 3) * 8 + (s & 7);
                VF[off] = f2bf(acc[t][r] + bd);
            }
        }
    }
}

// ---------------- K2: causal flash attention (R6/R8 structure, proven).
// Change this round: Po partials are written in A-FRAGMENT-MAJOR f32 so the
// fused oproj can load them as lane-linear bursts:
//   value Oacc[u][r] (row16=quad*4+r, d=u*16+cl) of group g16=w goes to
//   Po[bid*4096 + w*1024 + (u>>1)*512 + lane'*8 + (cl&7)],
//   lane' = ((u&1)*2 + (cl>>3))*16 + quad*4 + r   (MFMA A: lane=(k>>3)*16+row)
#define PSTR 152
__global__ __launch_bounds__(256, 2) void attn_kernel(
    const unsigned short* __restrict__ Qb, const unsigned short* __restrict__ Kb,
    const unsigned short* __restrict__ Vt,
    float* __restrict__ Po, float* __restrict__ Pl)
{
    __shared__ float4 shraw[4][304];
    const int bid = blockIdx.x;              // 0..1023
    const int pair = bid >> 2, h = bid & 3;
    const int a = 63 - (pair >> 2);
    const int b = pair & 3;
    const int q0 = a * 64;
    const int nkt = a + 1;
    const int kt0 = (h * nkt) >> 2;
    const int kt1 = ((h + 1) * nkt) >> 2;
    const int tid = threadIdx.x;
    const int w = tid >> 6, lane = tid & 63, cl = lane & 15, quad = lane >> 4;

    const size_t qrow = (size_t)b * S_LEN + q0 + w * 16 + cl;
    const bf16x8 aq0 = *(const bf16x8*)(const void*)(Qb + qrow * 64 + quad * 8);
    const bf16x8 aq1 = *(const bf16x8*)(const void*)(Qb + qrow * 64 + 32 + quad * 8);
    const unsigned short* kbb = Kb + (size_t)b * S_LEN * 64;
    const unsigned short* vbb = Vt + (size_t)b * S_LEN * 64;
    const int qm = q0 + w * 16 + quad * 4;

    float lrow[4];
    floatx4 Oacc[4];
    #pragma unroll
    for (int r = 0; r < 4; r++) lrow[r] = 0.f;
    #pragma unroll
    for (int u = 0; u < 4; u++) Oacc[u] = (floatx4){0.f, 0.f, 0.f, 0.f};

    unsigned short* Pw = (unsigned short*)&shraw[w][0];

    int jt = kt0;
    for (; jt + 1 < kt1; jt += 2) {
        __syncthreads();
        float z[8][4];
        bf16x8 vf[8][2];
        {
            bf16x8 kf[4][2];
            #pragma unroll
            for (int t = 0; t < 4; t++) {
                const unsigned short* kp = kbb + ((size_t)(jt * 4 + t) * 8 + quad) * 128 + cl * 8;
                kf[t][0] = *(const bf16x8*)(const void*)kp;
                kf[t][1] = *(const bf16x8*)(const void*)(kp + 512);
            }
            #pragma unroll
            for (int t = 0; t < 4; t++) {
                floatx4 acc = (floatx4){0.f, 0.f, 0.f, 0.f};
                acc = __builtin_amdgcn_mfma_f32_16x16x32_bf16(aq0, kf[t][0], acc, 0, 0, 0);
                acc = __builtin_amdgcn_mfma_f32_16x16x32_bf16(aq1, kf[t][1], acc, 0, 0, 0);
                #pragma unroll
                for (int r = 0; r < 4; r++) z[t][r] = acc[r];
            }
        }
        #pragma unroll
        for (int u = 0; u < 4; u++) {
            const unsigned short* vp = vbb + (size_t)jt * 4096 + u * 512 + cl * 32 + quad * 8;
            vf[u][0] = *(const bf16x8*)(const void*)vp;
            vf[u][1] = *(const bf16x8*)(const void*)(vp + 2048);
        }
        {
            bf16x8 kf[4][2];
            #pragma unroll
            for (int t = 0; t < 4; t++) {
                const unsigned short* kp = kbb + ((size_t)((jt + 1) * 4 + t) * 8 + quad) * 128 + cl * 8;
                kf[t][0] = *(const bf16x8*)(const void*)kp;
                kf[t][1] = *(const bf16x8*)(const void*)(kp + 512);
            }
            #pragma unroll
            for (int t = 0; t < 4; t++) {
                floatx4 acc = (floatx4){0.f, 0.f, 0.f, 0.f};
                acc = __builtin_amdgcn_mfma_f32_16x16x32_bf16(aq0, kf[t][0], acc, 0, 0, 0);
                acc = __builtin_amdgcn_mfma_f32_16x16x32_bf16(aq1, kf[t][1], acc, 0, 0, 0);
                #pragma unroll
                for (int r = 0; r < 4; r++) z[4 + t][r] = acc[r];
            }
        }
        #pragma unroll
        for (int u = 0; u < 4; u++) {
            const unsigned short* vp = vbb + (size_t)(jt + 1) * 4096 + u * 512 + cl * 32 + quad * 8;
            vf[4 + u][0] = *(const bf16x8*)(const void*)vp;
            vf[4 + u][1] = *(const bf16x8*)(const void*)(vp + 2048);
        }
        if (jt + 1 == nkt - 1) {
            const int j0b = (jt + 1) * 64;
            #pragma unroll
            for (int t = 0; t < 4; t++)
                #pragma unroll
                for (int r = 0; r < 4; r++)
                    if (j0b + t * 16 + cl > qm + r) z[4 + t][r] = -1e30f;
        }
        #pragma unroll
        for (int t = 0; t < 8; t++)
            #pragma unroll
            for (int r = 0; r < 4; r++) z[t][r] = fexp2(z[t][r]);
        #pragma unroll
        for (int r = 0; r < 4; r++)
            lrow[r] += ((z[0][r] + z[1][r]) + (z[2][r] + z[3][r]))
                     + ((z[4][r] + z[5][r]) + (z[6][r] + z[7][r]));
        #pragma unroll
        for (int t = 0; t < 8; t++)
            #pragma unroll
            for (int r = 0; r < 4; r++)
                Pw[(quad * 4 + r) * PSTR + t * 16 + cl] = f2bf(z[t][r]);
        bf16x8 ap0 = *(const bf16x8*)(const void*)(Pw + cl * PSTR + quad * 8);
        bf16x8 ap1 = *(const bf16x8*)(const void*)(Pw + cl * PSTR + 32 + quad * 8);
        bf16x8 ap2 = *(const bf16x8*)(const void*)(Pw + cl * PSTR + 64 + quad * 8);
        bf16x8 ap3 = *(const bf16x8*)(const void*)(Pw + cl * PSTR + 96 + quad * 8);
        #pragma unroll
        for (int u = 0; u < 4; u++) {
            Oacc[u] = __builtin_amdgcn_mfma_f32_16x16x32_bf16(ap0, vf[u][0], Oacc[u], 0, 0, 0);
            Oacc[u] = __builtin_amdgcn_mfma_f32_16x16x32_bf16(ap1, vf[u][1], Oacc[u], 0, 0, 0);
            Oacc[u] = __builtin_amdgcn_mfma_f32_16x16x32_bf16(ap2, vf[4 + u][0], Oacc[u], 0, 0, 0);
            Oacc[u] = __builtin_amdgcn_mfma_f32_16x16x32_bf16(ap3, vf[4 + u][1], Oacc[u], 0, 0, 0);
        }
    }
    if (jt < kt1) {
        bf16x8 kf[4][2], vf[4][2];
        #pragma unroll
        for (int t = 0; t < 4; t++) {
            const unsigned short* kp = kbb + ((size_t)(jt * 4 + t) * 8 + quad) * 128 + cl * 8;
            kf[t][0] = *(const bf16x8*)(const void*)kp;
            kf[t][1] = *(const bf16x8*)(const void*)(kp + 512);
        }
        #pragma unroll
        for (int u = 0; u < 4; u++) {
            const unsigned short* vp = vbb + (size_t)jt * 4096 + u * 512 + cl * 32 + quad * 8;
            vf[u][0] = *(const bf16x8*)(const void*)vp;
            vf[u][1] = *(const bf16x8*)(const void*)(vp + 2048);
        }
        float z[4][4];
        #pragma unroll
        for (int t = 0; t < 4; t++) {
            floatx4 acc = (floatx4){0.f, 0.f, 0.f, 0.f};
            acc = __builtin_amdgcn_mfma_f32_16x16x32_bf16(aq0, kf[t][0], acc, 0, 0, 0);
            acc = __builtin_amdgcn_mfma_f32_16x16x32_bf16(aq1, kf[t][1], acc, 0, 0, 0);
            #pragma unroll
            for (int r = 0; r < 4; r++) z[t][r] = acc[r];
        }
        if (jt == nkt - 1) {
            const int j0 = jt * 64;
            #pragma unroll
            for (int t = 0; t < 4; t++)
                #pragma unroll
                for (int r = 0; r < 4; r++)
                    if (j0 + t * 16 + cl > qm + r) z[t][r] = -1e30f;
        }
        #pragma unroll
        for (int t = 0; t < 4; t++)
            #pragma unroll
            for (int r = 0; r < 4; r++) z[t][r] = fexp2(z[t][r]);
        #pragma unroll
        for (int r = 0; r < 4; r++)
            lrow[r] += ((z[0][r] + z[1][r]) + (z[2][r] + z[3][r]));
        #pragma unroll
        for (int t = 0; t < 4; t++)
            #pragma unroll
            for (int r = 0; r < 4; r++)
                Pw[(quad * 4 + r) * PSTR + t * 16 + cl] = f2bf(z[t][r]);
        bf16x8 ap0 = *(const bf16x8*)(const void*)(Pw + cl * PSTR + quad * 8);
        bf16x8 ap1 = *(const bf16x8*)(const void*)(Pw + cl * PSTR + 32 + quad * 8);
        #pragma unroll
        for (int u = 0; u < 4; u++) {
            Oacc[u] = __builtin_amdgcn_mfma_f32_16x16x32_bf16(ap0, vf[u][0], Oacc[u], 0, 0, 0);
            Oacc[u] = __builtin_amdgcn_mfma_f32_16x16x32_bf16(ap1, vf[u][1], Oacc[u], 0, 0, 0);
        }
    }
    #pragma unroll
    for (int r = 0; r < 4; r++) {
        float s = lrow[r];
        s += __shfl_xor(s, 1, 64);
        s += __shfl_xor(s, 2, 64);
        s += __shfl_xor(s, 4, 64);
        s += __shfl_xor(s, 8, 64);
        lrow[r] = s;
    }
    // write unnormalized partial in A-fragment-major f32 (for fused oproj)
    {
        float* pob = Po + (size_t)bid * 4096 + w * 1024;
        #pragma unroll
        for (int u = 0; u < 4; u++) {
            const int base = (u >> 1) * 512
                           + (((u & 1) * 2 + (cl >> 3)) * 16 + quad * 4) * 8 + (cl & 7);
            #pragma unroll
            for (int r = 0; r < 4; r++)
                pob[base + r * 8] = Oacc[u][r];
        }
        if (cl == 0) {
            #pragma unroll
            for (int r = 0; r < 4; r++)
                Pl[(size_t)bid * 64 + w * 16 + quad * 4 + r] = lrow[r];
        }
    }
}

// ---------------- K3: FUSED merge + out-projection.
// Sums the 4 split-K Po partials (lane-linear f32x8 bursts), normalizes by
// invL (per-row = lane&15), converts to bf16 A-frags, then O @ Wo + bo.
__global__ __launch_bounds__(256) void oproj_kernel(
    const float* __restrict__ Po, const float* __restrict__ Pl,
    const unsigned short* __restrict__ WoF,
    const float* __restrict__ bo, float* __restrict__ out)
{
    const int blk = blockIdx.x;              // 0..1023, 16 rows each
    const int row0 = blk * 16;
    const int b = row0 >> 12, s0 = row0 & 4095;
    const int a = s0 >> 6, g16 = (s0 >> 4) & 3;
    const int pair = (63 - a) * 4 + b;       // attn pair for this (a,b)
    const int tid = threadIdx.x;
    const int w = tid >> 6, lane = tid & 63, cl = lane & 15, quad = lane >> 4;

    // sum the 4 partials for this 16-row group (both d-halves)
    float s0v[8], s1v[8];
    #pragma unroll
    for (int e = 0; e < 8; e++) { s0v[e] = 0.f; s1v[e] = 0.f; }
    #pragma unroll
    for (int h = 0; h < 4; h++) {
        const float* p = Po + ((size_t)(pair * 4 + h) * 4 + g16) * 1024 + lane * 8;
        #pragma unroll
        for (int e = 0; e < 8; e++) s0v[e] += p[e];
        #pragma unroll
        for (int e = 0; e < 8; e++) s1v[e] += p[512 + e];
    }
    float L = 0.f;
    #pragma unroll
    for (int h = 0; h < 4; h++)
        L += Pl[(size_t)(pair * 4 + h) * 64 + g16 * 16 + cl];
    const float invL = 1.0f / L;             // row for this lane = cl

    bf16x8 a0, a1;
    #pragma unroll
    for (int e = 0; e < 8; e++) {
        a0[e] = (__bf16)(s0v[e] * invL);
        a1[e] = (__bf16)(s1v[e] * invL);
    }

    #pragma unroll 2
    for (int i = 0; i < 8; i++) {
        const int g = w * 8 + i;
        const int n = g * 16 + cl;
        bf16x8 b0 = *(const bf16x8*)(const void*)(WoF + (size_t)(g * 2 + 0) * 512 + lane * 8);
        bf16x8 b1 = *(const bf16x8*)(const void*)(WoF + (size_t)(g * 2 + 1) * 512 + lane * 8);
        floatx4 acc = (floatx4){0.f, 0.f, 0.f, 0.f};
        acc = __builtin_amdgcn_mfma_f32_16x16x32_bf16(a0, b0, acc, 0, 0, 0);
        acc = __builtin_amdgcn_mfma_f32_16x16x32_bf16(a1, b1, acc, 0, 0, 0);
        const float bod = bo[n];
        #pragma unroll
        for (int r = 0; r < 4; r++)
            out[(size_t)(row0 + quad * 4 + r) * 512 + n] = acc[r] + bod;
    }
}

extern "C" void kernel_launch(void* const* d_in, const int* in_sizes, int n_in,
                              void* d_out, int out_size, void* d_ws, size_t ws_size,
                              hipStream_t stream) {
    const float* x  = (const float*)d_in[0];
    const float* Wq = (const float*)d_in[1];
    const float* bq = (const float*)d_in[2];
    const float* Wk = (const float*)d_in[3];
    const float* bk = (const float*)d_in[4];
    const float* Wv = (const float*)d_in[5];
    const float* bv = (const float*)d_in[6];
    const float* Wo = (const float*)d_in[7];
    const float* bo = (const float*)d_in[8];
    float* out = (float*)d_out;

    unsigned short* Qb  = (unsigned short*)d_ws;               // 2 MB
    unsigned short* KF  = Qb + (size_t)NROWS * 64;             // 2 MB (fragment-major)
    unsigned short* VF  = KF + (size_t)NROWS * 64;             // 2 MB (fragment-major)
    unsigned short* WqF = VF + (size_t)NROWS * 64;             // 64 KB each
    unsigned short* WkF = WqF + 512 * 64;
    unsigned short* WvF = WkF + 512 * 64;
    unsigned short* WoF = WvF + 512 * 64;
    float* Pl = (float*)(WoF + 512 * 64);                      // 1024*64 f32 = 256 KB
    float* Po = Pl + (size_t)1024 * 64;                        // 1024*4096 f32 = 16 MB
    // (Po must be in workspace, not d_out: fused oproj reads Po while
    //  writing out -- no kernel boundary separates them anymore.)

    convw_kernel<<<128, 256, 0, stream>>>(Wq, Wk, Wv, Wo, WqF, WkF, WvF, WoF);
    qkv_kernel<<<1024, 192, 0, stream>>>(x, WqF, WkF, WvF, bq, bk, bv, Qb, KF, VF);
    attn_kernel<<<1024, 256, 0, stream>>>(Qb, KF, VF, Po, Pl);
    oproj_kernel<<<NROWS / 16, 256, 0, stream>>>(Po, Pl, WoF, bo, out);
}